// Round 11
// baseline (292.990 us; speedup 1.0000x reference)
//
#include <hip/hip_runtime.h>
#include <hip/hip_bf16.h>
#include <stdint.h>

typedef __attribute__((ext_vector_type(4)))  float f32x4;
typedef __attribute__((ext_vector_type(16))) float f32x16;
typedef __attribute__((ext_vector_type(8)))  short bf16x8;

constexpr int IN_DIM  = 128;
constexpr int OUT_DIM = 128;
constexpr int BLOCK   = 256;              // 4 waves; wave w owns out cols w*32..+32
constexpr int TILE_ROWS = 32;             // 16 KB of f32 x per tile
constexpr int TILES_PER_BLOCK = 8;        // 256 rows per block
constexpr int ROWS_PER_BLOCK = TILE_ROWS * TILES_PER_BLOCK;
constexpr int NBUF = 2;                   // 32 KB LDS -> 5 blocks/CU (20 waves)

// v[o][k] = sign(round(sign)) * 2^round(clamp(shift,-14,0))  (exact in bf16)
__device__ __forceinline__ bf16x8 build_seg(const float* __restrict__ shiftp,
                                            const float* __restrict__ signp,
                                            int row, int j)
{
    const int g = row * IN_DIM + j * 8;
    f32x4 sh0 = *reinterpret_cast<const f32x4*>(shiftp + g);
    f32x4 sh1 = *reinterpret_cast<const f32x4*>(shiftp + g + 4);
    f32x4 sg0 = *reinterpret_cast<const f32x4*>(signp + g);
    f32x4 sg1 = *reinterpret_cast<const f32x4*>(signp + g + 4);
    union { ushort u[8]; bf16x8 v; } tmp;
    #pragma unroll
    for (int e = 0; e < 8; ++e) {
        float sh = (e < 4) ? sh0[e] : sh1[e - 4];
        float sg = (e < 4) ? sg0[e] : sg1[e - 4];
        sh = fminf(fmaxf(sh, -14.0f), 0.0f);
        const int   si = (int)rintf(sh);      // round-half-even like jnp.round
        const float rs = rintf(sg);           // {-1, 0, 1}
        ushort bits = 0;
        if (rs != 0.0f)
            bits = (ushort)(((rs < 0.0f) ? 0x8000u : 0u) |
                            (unsigned)((127 + si) << 7));  // exact 2^si in bf16
        tmp.u[e] = bits;
    }
    return tmp.v;
}

// Coalesced global -> LDS stage of one 32x128 f32 tile (16 KB), with XOR
// pre-swizzle on the GLOBAL side (rule #21): LDS chunk (row, c') holds global
// chunk (row, c' ^ (row&7)); the fragment read applies the same XOR. The XOR
// only permutes 16B chunks WITHIN each 128B line, so global requests still
// cover whole lines. Each gll: wave-uniform LDS base + lane*16B = 1024 B.
__device__ __forceinline__ void stage_tile(const float* __restrict__ gtile,
                                           float* __restrict__ lbuf,
                                           int wave, int lane)
{
    #pragma unroll
    for (int i = 0; i < 4; ++i) {
        const int seg = wave * 4 + i;           // 16 segs of 1 KB per tile
        const int p   = seg * 64 + lane;        // 16B-chunk index 0..1023
        const int row = p >> 5;                 // 32 chunks per 512B row
        const int cl  = p & 31;
        const int cg  = cl ^ (row & 7);         // inverse swizzle on source
        const float* g = gtile + row * IN_DIM + cg * 4;
        __builtin_amdgcn_global_load_lds(
            (const __attribute__((address_space(1))) unsigned int*)(uintptr_t)g,
            (__attribute__((address_space(3))) unsigned int*)(uintptr_t)(lbuf + seg * 256),
            16, 0, 0);
    }
}

// Main: mfma_f32_32x32x16_bf16, A = x rows (from LDS), B = v^T (registers).
// D: col o = ct*32 + (lane&31), row m = (r&3) + 8*(r>>2) + 4*(lane>>5)
// -> each store writes 2 full 128B lines (HW-verified round 5).
// Stores NON-TEMPORAL (round-9 win: keeps x Infinity-Cache-resident; steady
// state HBM = write stream only).
//
// Double-buffer, prefetch distance 1, store-aware counted wait:
// at top of iter tl the only vmem ops newer than gll(tl) are the 16 nt
// stores of tile tl-1 -> vmcnt(16) guarantees the tile is readable while
// stores stay in flight. tl=0 has only gll(0) outstanding -> vmcnt(0).
__global__ __launch_bounds__(BLOCK, 5)
void linshift_main(const float* __restrict__ x,
                   const float* __restrict__ shiftp,
                   const float* __restrict__ signp,
                   const float* __restrict__ biasp,
                   float* __restrict__ out)
{
    __shared__ float xbuf[NBUF][TILE_ROWS * IN_DIM];   // 2 x 16 KB

    const int t    = threadIdx.x;
    const int ct   = t >> 6;        // wave id = output column block
    const int lane = t & 63;
    const int ml   = lane & 31;     // A-row / D-col within 32
    const int hi   = lane >> 5;
    const int o    = ct * 32 + ml;  // this thread's output column

    // loop-invariant B fragments (built in-register; shift/sign are L2-hot)
    bf16x8 vb[8];
    #pragma unroll
    for (int ks = 0; ks < 8; ++ks)
        vb[ks] = build_seg(shiftp, signp, o, ks * 2 + hi);
    const float bv = floorf(biasp[o] * 65536.0f) * (1.0f / 65536.0f);  // round_to_fixed

    const long long brow0 = (long long)blockIdx.x * ROWS_PER_BLOCK;
    const float* xblock = x + brow0 * IN_DIM;

    // prologue: prefetch tile 0
    stage_tile(xblock, xbuf[0], ct, lane);

    const int swz = ml & 7;
    #pragma unroll
    for (int tl = 0; tl < TILES_PER_BLOCK; ++tl) {
        if (tl == 0) asm volatile("s_waitcnt vmcnt(0)"  ::: "memory");
        else         asm volatile("s_waitcnt vmcnt(16)" ::: "memory");
        __builtin_amdgcn_s_barrier();            // all waves' gll(tl) done; and all
        __builtin_amdgcn_sched_barrier(0);       // waves done reading tile tl-1

        // prefetch next tile into the buffer tile tl-1 occupied (safe: all
        // waves consumed tl-1's ds_reads into MFMAs before reaching the barrier)
        if (tl + 1 < TILES_PER_BLOCK)
            stage_tile(xblock + (long long)(tl + 1) * TILE_ROWS * IN_DIM,
                       xbuf[(tl + 1) & 1], ct, lane);

        const float* buf = xbuf[tl & 1];

        // A fragments: row ml, k = ks*16 + hi*8 .. +8 (swizzled chunks)
        bf16x8 a[8];
        #pragma unroll
        for (int ks = 0; ks < 8; ++ks) {
            const int c0 = ks * 4 + hi * 2;                  // even chunk index
            f32x4 f0 = *reinterpret_cast<const f32x4*>(&buf[ml * IN_DIM + ((c0 ^ swz) << 2)]);
            f32x4 f1 = *reinterpret_cast<const f32x4*>(&buf[ml * IN_DIM + (((c0 + 1) ^ swz) << 2)]);
            union { ushort u[8]; bf16x8 v; } tmp;
            #pragma unroll
            for (int e = 0; e < 4; ++e) {
                __hip_bfloat16 h0 = __float2bfloat16(f0[e]);
                __hip_bfloat16 h1 = __float2bfloat16(f1[e]);
                tmp.u[e]     = *reinterpret_cast<const ushort*>(&h0);
                tmp.u[e + 4] = *reinterpret_cast<const ushort*>(&h1);
            }
            a[ks] = tmp.v;
        }

        f32x16 acc;
        #pragma unroll
        for (int r = 0; r < 16; ++r) acc[r] = bv;    // bias folded into acc init
        #pragma unroll
        for (int ks = 0; ks < 8; ++ks)
            acc = __builtin_amdgcn_mfma_f32_32x32x16_bf16(a[ks], vb[ks], acc, 0, 0, 0);

        float* op = out + (brow0 + (long long)tl * TILE_ROWS) * OUT_DIM + o;
        #pragma unroll
        for (int r = 0; r < 16; ++r) {
            const int m = (r & 3) + 8 * (r >> 2) + 4 * hi;
            __builtin_nontemporal_store(acc[r], op + m * OUT_DIM);
        }
        __builtin_amdgcn_sched_barrier(0);
    }
}

extern "C" void kernel_launch(void* const* d_in, const int* in_sizes, int n_in,
                              void* d_out, int out_size, void* d_ws, size_t ws_size,
                              hipStream_t stream) {
    const float* x  = (const float*)d_in[0];
    const float* sh = (const float*)d_in[1];
    const float* sg = (const float*)d_in[2];
    const float* b  = (const float*)d_in[3];
    float* out = (float*)d_out;

    const int N = in_sizes[0] / IN_DIM;            // 524288
    const int grid = N / ROWS_PER_BLOCK;           // 2048 (exact)
    linshift_main<<<grid, BLOCK, 0, stream>>>(x, sh, sg, b, out);
}

// Round 12
// 97.205 us; speedup vs baseline: 3.0142x; 3.0142x over previous
//
#include <hip/hip_runtime.h>
#include <hip/hip_bf16.h>
#include <stdint.h>

typedef __attribute__((ext_vector_type(4)))  float f32x4;
typedef __attribute__((ext_vector_type(16))) float f32x16;
typedef __attribute__((ext_vector_type(8)))  short bf16x8;

constexpr int IN_DIM  = 128;
constexpr int OUT_DIM = 128;
constexpr int BLOCK   = 256;              // 4 waves; wave w owns out cols w*32..+32
constexpr int TILE_ROWS = 32;             // 16 KB of f32 x per tile
constexpr int TILES_PER_BLOCK = 8;        // 256 rows per block
constexpr int ROWS_PER_BLOCK = TILE_ROWS * TILES_PER_BLOCK;
constexpr int NBUF = 2;                   // 32 KB LDS -> 5 blocks/CU (LDS-limited)

// v[o][k] = sign(round(sign)) * 2^round(clamp(shift,-14,0))  (exact in bf16)
__device__ __forceinline__ bf16x8 build_seg(const float* __restrict__ shiftp,
                                            const float* __restrict__ signp,
                                            int row, int j)
{
    const int g = row * IN_DIM + j * 8;
    f32x4 sh0 = *reinterpret_cast<const f32x4*>(shiftp + g);
    f32x4 sh1 = *reinterpret_cast<const f32x4*>(shiftp + g + 4);
    f32x4 sg0 = *reinterpret_cast<const f32x4*>(signp + g);
    f32x4 sg1 = *reinterpret_cast<const f32x4*>(signp + g + 4);
    union { ushort u[8]; bf16x8 v; } tmp;
    #pragma unroll
    for (int e = 0; e < 8; ++e) {
        float sh = (e < 4) ? sh0[e] : sh1[e - 4];
        float sg = (e < 4) ? sg0[e] : sg1[e - 4];
        sh = fminf(fmaxf(sh, -14.0f), 0.0f);
        const int   si = (int)rintf(sh);      // round-half-even like jnp.round
        const float rs = rintf(sg);           // {-1, 0, 1}
        ushort bits = 0;
        if (rs != 0.0f)
            bits = (ushort)(((rs < 0.0f) ? 0x8000u : 0u) |
                            (unsigned)((127 + si) << 7));  // exact 2^si in bf16
        tmp.u[e] = bits;
    }
    return tmp.v;
}

// Coalesced global -> LDS stage of one 32x128 f32 tile (16 KB), with XOR
// pre-swizzle on the GLOBAL side (rule #21): LDS chunk (row, c') holds global
// chunk (row, c' ^ (row&7)); the fragment read applies the same XOR. The XOR
// only permutes 16B chunks WITHIN each 128B line, so global requests still
// cover whole lines. Each gll: wave-uniform LDS base + lane*16B = 1024 B.
__device__ __forceinline__ void stage_tile(const float* __restrict__ gtile,
                                           float* __restrict__ lbuf,
                                           int wave, int lane)
{
    #pragma unroll
    for (int i = 0; i < 4; ++i) {
        const int seg = wave * 4 + i;           // 16 segs of 1 KB per tile
        const int p   = seg * 64 + lane;        // 16B-chunk index 0..1023
        const int row = p >> 5;                 // 32 chunks per 512B row
        const int cl  = p & 31;
        const int cg  = cl ^ (row & 7);         // inverse swizzle on source
        const float* g = gtile + row * IN_DIM + cg * 4;
        __builtin_amdgcn_global_load_lds(
            (const __attribute__((address_space(1))) unsigned int*)(uintptr_t)g,
            (__attribute__((address_space(3))) unsigned int*)(uintptr_t)(lbuf + seg * 256),
            16, 0, 0);
    }
}

// Main: mfma_f32_32x32x16_bf16, A = x rows (from LDS), B = v^T (registers).
// D: col o = ct*32 + (lane&31), row m = (r&3) + 8*(r>>2) + 4*(lane>>5)
// -> each store writes 2 full 128B lines (HW-verified round 5).
// Stores NON-TEMPORAL (round-9 win: steady-state HBM = write stream only,
// x stays Infinity-Cache-resident across replays).
//
// Occupancy: 32 KB LDS -> 5 blocks/CU (20 waves). launch_bounds min-waves
// stays 3 — rounds 10/11 proved tighter bounds clamp VGPR below the ~84
// this kernel needs and spill to scratch (FETCH 566 MB, 3x regression).
//
// Counted wait: at top of iter tl, outstanding vmem (this wave) =
// gll(tl) x4 (oldest) + nt-stores of tl-1 x16 (+ maybe older store residue).
// vmcnt(16) -> gll(tl) complete, newest 16 stores may remain in flight.
__global__ __launch_bounds__(BLOCK, 3)
void linshift_main(const float* __restrict__ x,
                   const float* __restrict__ shiftp,
                   const float* __restrict__ signp,
                   const float* __restrict__ biasp,
                   float* __restrict__ out)
{
    __shared__ float xbuf[NBUF][TILE_ROWS * IN_DIM];   // 2 x 16 KB

    const int t    = threadIdx.x;
    const int ct   = t >> 6;        // wave id = output column block
    const int lane = t & 63;
    const int ml   = lane & 31;     // A-row / D-col within 32
    const int hi   = lane >> 5;
    const int o    = ct * 32 + ml;  // this thread's output column

    // loop-invariant B fragments (built in-register; shift/sign are L2-hot)
    bf16x8 vb[8];
    #pragma unroll
    for (int ks = 0; ks < 8; ++ks)
        vb[ks] = build_seg(shiftp, signp, o, ks * 2 + hi);
    const float bv = floorf(biasp[o] * 65536.0f) * (1.0f / 65536.0f);  // round_to_fixed

    const long long brow0 = (long long)blockIdx.x * ROWS_PER_BLOCK;
    const float* xblock = x + brow0 * IN_DIM;

    // prologue: prefetch tile 0
    stage_tile(xblock, xbuf[0], ct, lane);

    const int swz = ml & 7;
    #pragma unroll
    for (int tl = 0; tl < TILES_PER_BLOCK; ++tl) {
        if (tl == 0) asm volatile("s_waitcnt vmcnt(0)"  ::: "memory");
        else         asm volatile("s_waitcnt vmcnt(16)" ::: "memory");
        __builtin_amdgcn_s_barrier();            // all waves' gll(tl) done; and all
        __builtin_amdgcn_sched_barrier(0);       // waves done reading tile tl-1

        // prefetch next tile into the buffer tile tl-1 used (safe: every wave
        // consumed tl-1's ds_reads into MFMAs before it reached the barrier)
        if (tl + 1 < TILES_PER_BLOCK)
            stage_tile(xblock + (long long)(tl + 1) * TILE_ROWS * IN_DIM,
                       xbuf[(tl + 1) & 1], ct, lane);

        const float* buf = xbuf[tl & 1];

        // A fragments: row ml, k = ks*16 + hi*8 .. +8 (swizzled chunks)
        bf16x8 a[8];
        #pragma unroll
        for (int ks = 0; ks < 8; ++ks) {
            const int c0 = ks * 4 + hi * 2;                  // even chunk index
            f32x4 f0 = *reinterpret_cast<const f32x4*>(&buf[ml * IN_DIM + ((c0 ^ swz) << 2)]);
            f32x4 f1 = *reinterpret_cast<const f32x4*>(&buf[ml * IN_DIM + (((c0 + 1) ^ swz) << 2)]);
            union { ushort u[8]; bf16x8 v; } tmp;
            #pragma unroll
            for (int e = 0; e < 4; ++e) {
                __hip_bfloat16 h0 = __float2bfloat16(f0[e]);
                __hip_bfloat16 h1 = __float2bfloat16(f1[e]);
                tmp.u[e]     = *reinterpret_cast<const ushort*>(&h0);
                tmp.u[e + 4] = *reinterpret_cast<const ushort*>(&h1);
            }
            a[ks] = tmp.v;
        }

        f32x16 acc;
        #pragma unroll
        for (int r = 0; r < 16; ++r) acc[r] = bv;    // bias folded into acc init
        #pragma unroll
        for (int ks = 0; ks < 8; ++ks)
            acc = __builtin_amdgcn_mfma_f32_32x32x16_bf16(a[ks], vb[ks], acc, 0, 0, 0);

        float* op = out + (brow0 + (long long)tl * TILE_ROWS) * OUT_DIM + o;
        #pragma unroll
        for (int r = 0; r < 16; ++r) {
            const int m = (r & 3) + 8 * (r >> 2) + 4 * hi;
            __builtin_nontemporal_store(acc[r], op + m * OUT_DIM);
        }
        __builtin_amdgcn_sched_barrier(0);
    }
}

extern "C" void kernel_launch(void* const* d_in, const int* in_sizes, int n_in,
                              void* d_out, int out_size, void* d_ws, size_t ws_size,
                              hipStream_t stream) {
    const float* x  = (const float*)d_in[0];
    const float* sh = (const float*)d_in[1];
    const float* sg = (const float*)d_in[2];
    const float* b  = (const float*)d_in[3];
    float* out = (float*)d_out;

    const int N = in_sizes[0] / IN_DIM;            // 524288
    const int grid = N / ROWS_PER_BLOCK;           // 2048 (exact)
    linshift_main<<<grid, BLOCK, 0, stream>>>(x, sh, sg, b, out);
}